// Round 6
// baseline (384.258 us; speedup 1.0000x reference)
//
#include <hip/hip_runtime.h>

// YOLO loss: S=7, B=2, C=80. preds cell = 90 f32, target cell = 85 f32.
// Output: 4 f32 scalars (coords, obj, noobj, classes) over 401408 cells.
//
// R6: barrier-free flat split. Proven walls so far:
//   (a) scattered-address TA wall: thread-per-cell => 64 L1-line touches per
//       VMEM instr, ~1 line/cyc/CU  (R1: 126 instrs/cell -> 141us model ~ 147us meas)
//   (b) barrier/latency serialization in all LDS-tiled variants (R2/R4/R5
//       all ~153-227us; L3-resident replays SAME dur => bytes not the wall).
// Fix: class loss (80/90 of bytes) via flat lane-consecutive element scan --
// every load touches ~2 lines/instr; box terms via a light thread-per-cell
// pass (10 wave-instrs/cell, L3-hot after the scan). No LDS staging, no
// per-tile barriers, 4x unrolled independent loads, 32 waves/CU.

#define NPRED 90
#define NTGT  85
#define NCLS  80
#define BLOCK 256

__device__ __forceinline__ float sgnf(float x) {
    return (x > 0.0f) ? 1.0f : ((x < 0.0f) ? -1.0f : 0.0f);
}

__device__ __forceinline__ void class_elem(
    const float* __restrict__ preds, const float* __restrict__ targ,
    int j, float& clsl)
{
    unsigned cell = (unsigned)j / 90u;      // magic-mul
    int field = j - (int)cell * 90;
    if (field < NCLS) {
        float p   = preds[j];
        float tv  = targ[(int)cell * NTGT + field];  // lane-contiguous runs
        float obj = targ[(int)cell * NTGT + NCLS];   // 1-2 lines/wave, L1-hot
        float d = fmaf(p, obj, -tv);
        clsl = fmaf(d, d, clsl);
    }
}

__global__ __launch_bounds__(BLOCK) void yolo_loss_kernel(
    const float* __restrict__ preds, const float* __restrict__ targ,
    float* __restrict__ out, int n_cells)
{
    const int gtid = blockIdx.x * BLOCK + threadIdx.x;
    const int T    = gridDim.x * BLOCK;

    float coords = 0.0f, objl = 0.0f, noobjl = 0.0f, clsl = 0.0f;

    // ---- phase 1: flat class-loss scan, lane-consecutive j ----
    const int N = n_cells * NPRED;  // 36.1M, fits int
    int j = gtid;
    for (; j + 3 * T < N; j += 4 * T) {
        class_elem(preds, targ, j,         clsl);
        class_elem(preds, targ, j + T,     clsl);
        class_elem(preds, targ, j + 2 * T, clsl);
        class_elem(preds, targ, j + 3 * T, clsl);
    }
    for (; j < N; j += T) class_elem(preds, targ, j, clsl);

    // ---- phase 2: box terms, thread-per-cell (10 wave-instrs/cell) ----
    for (int c = gtid; c < n_cells; c += T) {
        const float* p = preds + (size_t)c * NPRED;
        const float* t = targ  + (size_t)c * NTGT;
        // (c*360+320) % 8 == 0 -> float2 loads of p[80..89] are aligned
        const float2* pb = (const float2*)(p + 80);
        float2 q0 = pb[0], q1 = pb[1], q2 = pb[2], q3 = pb[3], q4 = pb[4];
        float P80 = q0.x, P81 = q0.y, P82 = q1.x, P83 = q1.y, P84 = q2.x;
        float P85 = q2.y, P86 = q3.x, P87 = q3.y, P88 = q4.x, P89 = q4.y;
        float obj = t[80];
        float tcx = t[81], tcy = t[82], tw = t[83], th = t[84];

        float bx1 = tcx - tw * 0.5f, by1 = tcy - th * 0.5f;
        float bx2 = tcx + tw * 0.5f, by2 = tcy + th * 0.5f;
        float area_b = (bx2 - bx1) * (by2 - by1);

        // box1 = p[86..89]
        float ax1 = P86 - P88 * 0.5f, ay1 = P87 - P89 * 0.5f;
        float ax2 = P86 + P88 * 0.5f, ay2 = P87 + P89 * 0.5f;
        float iw = fmaxf(fminf(ax2, bx2) - fmaxf(ax1, bx1), 0.0f);
        float ih = fmaxf(fminf(ay2, by2) - fmaxf(ay1, by1), 0.0f);
        float inter1 = iw * ih;
        float area1 = (ax2 - ax1) * (ay2 - ay1);
        float iou1 = inter1 / (area1 + area_b - inter1);

        // box2 = p[81..84]
        float cx1 = P81 - P83 * 0.5f, cy1 = P82 - P84 * 0.5f;
        float cx2 = P81 + P83 * 0.5f, cy2 = P82 + P84 * 0.5f;
        float jw = fmaxf(fminf(cx2, bx2) - fmaxf(cx1, bx1), 0.0f);
        float jh = fmaxf(fminf(cy2, by2) - fmaxf(cy1, by1), 0.0f);
        float inter2 = jw * jh;
        float area2 = (cx2 - cx1) * (cy2 - cy1);
        float iou2 = inter2 / (area2 + area_b - inter2);

        bool use2 = iou2 > iou1;  // argmax: tie -> box1

        float pcx = obj * (use2 ? P81 : P86);
        float pw  = obj * (use2 ? P83 : P88);
        float ph  = obj * (use2 ? P84 : P89);

        // center loss uses ONLY cx (ref's [..., :-3] on a 4-vector)
        float dc = pcx - tcx;
        float dw = sgnf(pw) * sqrtf(fabsf(pw) + 1e-6f) - sqrtf(tw);
        float dh = sgnf(ph) * sqrtf(fabsf(ph) + 1e-6f) - sqrtf(th);
        coords = fmaf(dc, dc, coords);
        coords = fmaf(dw, dw, coords);
        coords = fmaf(dh, dh, coords);

        float obj_pred = use2 ? P80 : P85;
        float e1 = fmaf(obj, obj_pred, -obj);
        objl = fmaf(e1, e1, objl);
        float e2 = fmaf(1.0f - obj, obj_pred, -obj);
        noobjl = fmaf(e2, e2, noobjl);
    }

    // ---- wave reduce (64 lanes) ----
    #pragma unroll
    for (int off = 32; off > 0; off >>= 1) {
        coords += __shfl_down(coords, off);
        objl   += __shfl_down(objl, off);
        noobjl += __shfl_down(noobjl, off);
        clsl   += __shfl_down(clsl, off);
    }

    __shared__ float red[4][4];
    int wave = threadIdx.x >> 6;
    int lane = threadIdx.x & 63;
    if (lane == 0) {
        red[0][wave] = coords;
        red[1][wave] = objl;
        red[2][wave] = noobjl;
        red[3][wave] = clsl;
    }
    __syncthreads();
    if (threadIdx.x == 0) {
        float cd = red[0][0] + red[0][1] + red[0][2] + red[0][3];
        float o  = red[1][0] + red[1][1] + red[1][2] + red[1][3];
        float n  = red[2][0] + red[2][1] + red[2][2] + red[2][3];
        float k  = red[3][0] + red[3][1] + red[3][2] + red[3][3];
        atomicAdd(&out[0], 5.0f * cd);  // LAMBDA_COORDS
        atomicAdd(&out[1], o);
        atomicAdd(&out[2], 0.5f * n);   // LAMBDA_NOOBJ
        atomicAdd(&out[3], k);
    }
}

extern "C" void kernel_launch(void* const* d_in, const int* in_sizes, int n_in,
                              void* d_out, int out_size, void* d_ws, size_t ws_size,
                              hipStream_t stream) {
    const float* preds = (const float*)d_in[0];
    const float* targ  = (const float*)d_in[1];
    float* out = (float*)d_out;

    int n_cells = in_sizes[0] / NPRED;  // 401408

    hipMemsetAsync(d_out, 0, (size_t)out_size * sizeof(float), stream);

    // zero LDS, VGPR ~40 -> full 32 waves/CU; 2048 blocks = 8 blocks/CU
    int blocks = 2048;
    hipLaunchKernelGGL(yolo_loss_kernel, dim3(blocks), dim3(BLOCK), 0, stream,
                       preds, targ, out, n_cells);
}